// Round 4
// baseline (316.129 us; speedup 1.0000x reference)
//
#include <hip/hip_runtime.h>

// Problem: L=200 events consumed in pairs -> S=100 scan steps over u[N,N,3],
// N=256. Each (n,m) cell is an independent 100-step chain.
//
// Round-1 counters (monolithic, 1 wave/SIMD): 101 us, 1.55 TB/s (19.5%),
// VALUBusy 7%, Occupancy 10%. Latency-bound; BW scales ~linearly in
// waves/SIMD. Plan (unchanged from round 2 — infra failed twice, design
// re-audited for correctness instead):
//   kernel 1 (f_kernel): f[t,n] = exp(-dot(w[t,n,:],ev[t,n,:])*time[t&1])
//     one wave per (t,n) row -> ~50 waves/SIMD occupancy, streams the 105 MB
//     of w+ev at near-BW, writes f to workspace [N][T] (205 KB).
//   kernel 2 (scan_kernel): 4 lanes per chain -> 4096 waves = 4 waves/SIMD.
//     Lane sub = p + 2*par loads slab t = 4k + sub. shfl_xor(1) forms the
//     even-step slab-pair total in par-0 lanes and the odd-step total in
//     par-1 lanes; shfl_xor(2) swaps across parities; 2 scan steps per ring
//     slot. DD=10 static register ring per lane -> counted vmcnt,
//     120 B/lane in flight x 16 waves/CU.
//
// Layout facts:
//   event_list [201,256,256]  (use first 200 rows)
//   a          [200,256,256,3]
//   w          [200,256,1,256]
//   u_begin    [256,256,3]
//   liner_w    [256,3], liner_b [256]
//   out        [100,256,256]  float32

#define NN   256
#define TT   200
#define SS   100
#define DD   10            // ring depth in k (step-pairs); 50/DD groups
#define NG   (50 / DD)     // 5 groups of k

// ---------------- kernel 1: per-(t,n) dot + exp, high occupancy ----------------
__global__ __launch_bounds__(256) void f_kernel(
    const float* __restrict__ timep,   // [2]
    const float* __restrict__ ev,      // [201,N,N]
    const float* __restrict__ w,       // [T,N,1,N]
    float* __restrict__ fws)           // [N,T] workspace
{
    const int tid  = threadIdx.x;
    const int lane = tid & 63;
    const int row  = blockIdx.x * 4 + (tid >> 6);   // 0 .. 51199
    const int t    = row >> 8;                      // 0 .. 199
    const int n    = row & 255;

    const size_t off = (size_t)t * (NN * NN) + (size_t)n * NN;
    const float4 wv  = ((const float4*)(w  + off))[lane];
    const float4 evv = ((const float4*)(ev + off))[lane];

    float d = wv.x * evv.x;
    d = fmaf(wv.y, evv.y, d);
    d = fmaf(wv.z, evv.z, d);
    d = fmaf(wv.w, evv.w, d);
#pragma unroll
    for (int off2 = 1; off2 < 64; off2 <<= 1)
        d += __shfl_xor(d, off2, 64);

    if (lane == 0) {
        const float tsel = (t & 1) ? timep[1] : timep[0];
        fws[n * TT + t] = __expf(-d * tsel);
    }
}

// ---------------- kernel 2: the scan, 4 lanes per chain ----------------
__global__ __launch_bounds__(256, 4) void scan_kernel(
    const float* __restrict__ fws,     // [N,T]
    const float* __restrict__ ub,      // [N,N,3]
    const float* __restrict__ a,       // [T,N,N,3]
    const float* __restrict__ lw,      // [N,3]
    const float* __restrict__ lb,      // [N]
    float* __restrict__ out)           // [S,N,N]
{
    __shared__ float fs[TT];

    const int n    = blockIdx.x;
    const int qtr  = blockIdx.y;             // 0..3 -> which 64 chains
    const int tid  = threadIdx.x;
    const int sub  = tid & 3;                // p + 2*par
    const int par  = sub >> 1;               // step parity this lane serves
    const int chain = qtr * 64 + (tid >> 2); // global m in [0,256)

    if (tid < TT) fs[tid] = fws[n * TT + tid];

    const size_t TS    = (size_t)NN * NN * 3;    // floats per t-slab (196608)
    const size_t cbase = (size_t)n * (NN * 3) + (size_t)chain * 3;

    // chain state + per-node constants (identical across the 4 lanes)
    float u0 = ub[cbase + 0];
    float u1 = ub[cbase + 1];
    float u2 = ub[cbase + 2];
    const float w0 = lw[n * 3 + 0];
    const float w1 = lw[n * 3 + 1];
    const float w2 = lw[n * 3 + 2];
    const float bb = lb[n];

    __syncthreads();   // fs ready; ring preload AFTER the barrier so its
                       // vmcnt(0) drain doesn't serialize the ring

    // ---- depth-DD register ring; lane's slab for pair k is t = 4k + sub ----
    const float* pf = a + (size_t)sub * TS + cbase;   // k advances by 4*TS
    float rg[DD][3];
#pragma unroll
    for (int j = 0; j < DD; ++j) {
        rg[j][0] = pf[0];
        rg[j][1] = pf[1];
        rg[j][2] = pf[2];
        pf += 4 * TS;
    }

    float* op = out + (size_t)n * NN + chain;
    const bool sel = (par == 0);      // lane-constant select for step totals
    const bool st  = (sub == 0);      // storing lane

    for (int g = 0; g < NG; ++g) {
        const int kb = g * DD;
#pragma unroll
        for (int j = 0; j < DD; ++j) {
            const int k = kb + j;                 // step pair: s0=2k, s1=2k+1
            const float ff = fs[4 * k + sub];     // this lane's slab factor
            // contribution of this lane's slab to ITS step
            float v0 = rg[j][0] * ff;
            float v1 = rg[j][1] * ff;
            float v2 = rg[j][2] * ff;
            // slot j dead for this lane -> refill for pair k+DD
            if (g != NG - 1) {
                rg[j][0] = pf[0];
                rg[j][1] = pf[1];
                rg[j][2] = pf[2];
                pf += 4 * TS;
            }
            // combine p-pair: par-0 lanes get even-step total, par-1 odd-step
            float vv0 = v0 + __shfl_xor(v0, 1, 64);
            float vv1 = v1 + __shfl_xor(v1, 1, 64);
            float vv2 = v2 + __shfl_xor(v2, 1, 64);
            // cross-parity swap
            float b0 = __shfl_xor(vv0, 2, 64);
            float b1 = __shfl_xor(vv1, 2, 64);
            float b2 = __shfl_xor(vv2, 2, 64);
            // ---- step s0 = 2k ----
            {
                float l0 = u0 + (sel ? vv0 : b0);
                float l1 = u1 + (sel ? vv1 : b1);
                float l2 = u2 + (sel ? vv2 : b2);
                float mx  = fmaxf(l0, fmaxf(l1, l2));
                float e0  = __expf(l0 - mx);
                float e1  = __expf(l1 - mx);
                float e2  = __expf(l2 - mx);
                float inv = __builtin_amdgcn_rcpf(e0 + e1 + e2);
                u0 = e0 * inv;
                u1 = e1 * inv;
                u2 = e2 * inv;
                if (st) {
                    __builtin_nontemporal_store(
                        fmaf(u0, w0, fmaf(u1, w1, fmaf(u2, w2, bb))),
                        op + (size_t)(2 * k) * (NN * NN));
                }
            }
            // ---- step s1 = 2k+1 ----
            {
                float l0 = u0 + (sel ? b0 : vv0);
                float l1 = u1 + (sel ? b1 : vv1);
                float l2 = u2 + (sel ? b2 : vv2);
                float mx  = fmaxf(l0, fmaxf(l1, l2));
                float e0  = __expf(l0 - mx);
                float e1  = __expf(l1 - mx);
                float e2  = __expf(l2 - mx);
                float inv = __builtin_amdgcn_rcpf(e0 + e1 + e2);
                u0 = e0 * inv;
                u1 = e1 * inv;
                u2 = e2 * inv;
                if (st) {
                    __builtin_nontemporal_store(
                        fmaf(u0, w0, fmaf(u1, w1, fmaf(u2, w2, bb))),
                        op + (size_t)(2 * k + 1) * (NN * NN));
                }
            }
        }
    }
}

extern "C" void kernel_launch(void* const* d_in, const int* in_sizes, int n_in,
                              void* d_out, int out_size, void* d_ws, size_t ws_size,
                              hipStream_t stream) {
    const float* timep = (const float*)d_in[0];
    const float* ev    = (const float*)d_in[1];
    const float* ub    = (const float*)d_in[2];
    const float* a     = (const float*)d_in[3];
    const float* w     = (const float*)d_in[4];
    const float* lw    = (const float*)d_in[5];
    const float* lb    = (const float*)d_in[6];
    float* out = (float*)d_out;
    float* fws = (float*)d_ws;                 // needs 256*200*4 = 204800 B

    f_kernel<<<(TT * NN) / 4, 256, 0, stream>>>(timep, ev, w, fws);
    scan_kernel<<<dim3(NN, 4), 256, 0, stream>>>(fws, ub, a, lw, lb, out);
}

// Round 5
// 308.003 us; speedup vs baseline: 1.0264x; 1.0264x over previous
//
#include <hip/hip_runtime.h>

// Problem: L=200 events in pairs -> S=100 scan steps over u[N,N,3], N=256.
// Each (n,m) cell is an independent 100-step chain.
//
// History: r1 monolithic ring: scan ~101 us @1.55 TB/s, Occ 10%, VALU 7%.
// r4 split + 4 waves/SIMD: scan STILL ~90 us -> occupancy scaling REFUTED.
// Theory: per-CU outstanding-line cap + high latency on scattered 12-B/lane
// dword loads. Fix: block-cooperative contiguous staging of a[t][n][:][:]
// (3 KB/slab) via global_load_lds (16 B/lane, 1 KB/instr, m97 pattern),
// 6-deep LDS group ring, counted vmcnt (never 0) + raw s_barrier per phase.
//
// Layout: event_list[201,256,256], a[200,256,256,3], w[200,256,1,256],
//         u_begin[256,256,3], liner_w[256,3], liner_b[256], out[100,256,256].

#define NN    256
#define TT    200
#define SS    100
#define DRING 6            // LDS ring depth in groups (4 slabs = 2 steps each)

// ---------------- kernel 1: f[t,n] = exp(-dot*time), high occupancy ----------
__global__ __launch_bounds__(256) void f_kernel(
    const float* __restrict__ timep,
    const float* __restrict__ ev,
    const float* __restrict__ w,
    float* __restrict__ fws)           // [N,T]
{
    const int tid  = threadIdx.x;
    const int lane = tid & 63;
    const int row  = blockIdx.x * 4 + (tid >> 6);   // 0..51199
    const int t    = row >> 8;
    const int n    = row & 255;

    const size_t off = (size_t)t * (NN * NN) + (size_t)n * NN;
    const float4 wv  = ((const float4*)(w  + off))[lane];
    const float4 evv = ((const float4*)(ev + off))[lane];

    float d = wv.x * evv.x;
    d = fmaf(wv.y, evv.y, d);
    d = fmaf(wv.z, evv.z, d);
    d = fmaf(wv.w, evv.w, d);
#pragma unroll
    for (int o = 1; o < 64; o <<= 1) d += __shfl_xor(d, o, 64);

    if (lane == 0) {
        const float tsel = (t & 1) ? timep[1] : timep[0];
        fws[n * TT + t] = __expf(-d * tsel);
    }
}

// ---------------- kernel 2: the scan, LDS-staged contiguous a-stream ---------
__global__ __launch_bounds__(256) void scan_kernel(
    const float* __restrict__ fws,     // [N,T]
    const float* __restrict__ ub,      // [N,N,3]
    const float* __restrict__ a,       // [T,N,N,3]
    const float* __restrict__ lw,      // [N,3]
    const float* __restrict__ lb,      // [N]
    float* __restrict__ out)           // [S,N,N]
{
    __shared__ float stg[DRING][4][768];   // [ring][slab-in-group][m*3+c]
    __shared__ float fsl[TT];

    const int n    = blockIdx.x;
    const int tid  = threadIdx.x;
    const int lane = tid & 63;
    const int wv   = tid >> 6;             // wave id 0..3 (stages slab 4q+wv)

    if (tid < TT) fsl[tid] = fws[n * TT + tid];

    const size_t cb = (size_t)n * (NN * 3) + (size_t)tid * 3;
    float u0 = ub[cb + 0], u1 = ub[cb + 1], u2 = ub[cb + 2];
    const float w0 = lw[n * 3 + 0];
    const float w1 = lw[n * 3 + 1];
    const float w2 = lw[n * 3 + 2];
    const float bb = lb[n];

    const int m3 = tid * 3;
    float* op = out + (size_t)n * NN + tid;

    // drains vmcnt(0)+lgkmcnt(0): fsl + u loads complete BEFORE any stage
    // is issued, so the phase vmcnt counts below see only stages + stores.
    __syncthreads();

    // per-lane global src: 16 B/lane, 64 lanes = 1 KB per instruction
    const float* abase = a + (size_t)n * (NN * 3) + (size_t)lane * 4;

    // wave wv stages slab t=4q+wv of group q into stg[bidx][wv] (3 KB = 3 ops)
#define STAGE(qq, bidx)                                                        \
    do {                                                                       \
        const float* gp_ = abase + (size_t)(4 * (qq) + wv) * ((size_t)NN * NN * 3); \
        float* lp_ = &stg[bidx][wv][0];                                        \
        __builtin_amdgcn_global_load_lds(                                      \
            (const __attribute__((address_space(1))) void*)gp_,                \
            (__attribute__((address_space(3))) void*)lp_, 16, 0, 0);           \
        __builtin_amdgcn_global_load_lds(                                      \
            (const __attribute__((address_space(1))) void*)(gp_ + 256),        \
            (__attribute__((address_space(3))) void*)(lp_ + 256), 16, 0, 0);   \
        __builtin_amdgcn_global_load_lds(                                      \
            (const __attribute__((address_space(1))) void*)(gp_ + 512),        \
            (__attribute__((address_space(3))) void*)(lp_ + 512), 16, 0, 0);   \
    } while (0)

    // prologue: stage groups 0..4 into bufs 0..4 (15 loads in flight)
    STAGE(0, 0); STAGE(1, 1); STAGE(2, 2); STAGE(3, 3); STAGE(4, 4);

#define STEPX(BI, SA, SB, FA, FB, SOUT)                                        \
    do {                                                                       \
        float l0 = fmaf(stg[BI][SA][m3 + 0], FA, fmaf(stg[BI][SB][m3 + 0], FB, u0)); \
        float l1 = fmaf(stg[BI][SA][m3 + 1], FA, fmaf(stg[BI][SB][m3 + 1], FB, u1)); \
        float l2 = fmaf(stg[BI][SA][m3 + 2], FA, fmaf(stg[BI][SB][m3 + 2], FB, u2)); \
        float mx = fmaxf(l0, fmaxf(l1, l2));                                   \
        float e0 = __expf(l0 - mx), e1 = __expf(l1 - mx), e2 = __expf(l2 - mx);\
        float iv = __builtin_amdgcn_rcpf(e0 + e1 + e2);                        \
        u0 = e0 * iv; u1 = e1 * iv; u2 = e2 * iv;                              \
        __builtin_nontemporal_store(fmaf(u0, w0, fmaf(u1, w1, fmaf(u2, w2, bb))), \
                                    op + (size_t)(SOUT) * (NN * NN));          \
    } while (0)

    // Phase g: counted vmcnt (exact: 3 loads/stage, 2 stores/phase, in-order
    // vmcnt), raw s_barrier, stage group g+5 into buf (g-1)%6 (readers
    // finished last phase, separated by this barrier), consume group g
    // (slabs 4g..4g+3 = steps 2g, 2g+1). Memory-clobber asms pin the
    // stage-before-store order the vmcnt arithmetic assumes.
#define PHASE(GG, VN, DOSTAGE, BI)                                             \
    do {                                                                       \
        asm volatile("s_waitcnt vmcnt(" #VN ")" ::: "memory");                 \
        __builtin_amdgcn_s_barrier();                                          \
        asm volatile("" ::: "memory");                                         \
        if (DOSTAGE) {                                                         \
            const int bs_ = (BI) ? (BI) - 1 : (DRING - 1);                     \
            STAGE((GG) + DRING - 1, bs_);                                      \
        }                                                                      \
        asm volatile("" ::: "memory");                                         \
        const float fa0 = fsl[4 * (GG) + 0], fb0 = fsl[4 * (GG) + 1];          \
        STEPX(BI, 0, 1, fa0, fb0, 2 * (GG));                                   \
        const float fa1 = fsl[4 * (GG) + 2], fb1 = fsl[4 * (GG) + 3];          \
        STEPX(BI, 2, 3, fa1, fb1, 2 * (GG) + 1);                               \
    } while (0)

    // vmcnt(N) = #vm-ops younger than this group's stage (derived exactly):
    // g=0: S(1..4)=12 | g=1: +st0=14 | g=2: 16 | g=3: 18 | g=4: 20 | g>=5: 22
    PHASE(0, 12, 1, 0);
    PHASE(1, 14, 1, 1);
    PHASE(2, 16, 1, 2);
    PHASE(3, 18, 1, 3);
    PHASE(4, 20, 1, 4);
    {
        int b = 5;                        // b == g % 6, rolled manually
        for (int g = 5; g <= 44; ++g) {
            PHASE(g, 22, 1, b);
            b = (b == DRING - 1) ? 0 : b + 1;
        }
    }
    // tail: no staging left; counts shrink as stage queue drains
    PHASE(45, 22, 0, 3);
    PHASE(46, 19, 0, 4);
    PHASE(47, 16, 0, 5);
    PHASE(48, 13, 0, 0);
    PHASE(49, 10, 0, 1);

#undef PHASE
#undef STEPX
#undef STAGE
}

extern "C" void kernel_launch(void* const* d_in, const int* in_sizes, int n_in,
                              void* d_out, int out_size, void* d_ws, size_t ws_size,
                              hipStream_t stream) {
    const float* timep = (const float*)d_in[0];
    const float* ev    = (const float*)d_in[1];
    const float* ub    = (const float*)d_in[2];
    const float* a     = (const float*)d_in[3];
    const float* w     = (const float*)d_in[4];
    const float* lw    = (const float*)d_in[5];
    const float* lb    = (const float*)d_in[6];
    float* out = (float*)d_out;
    float* fws = (float*)d_ws;                 // needs 256*200*4 = 204800 B

    f_kernel<<<(TT * NN) / 4, 256, 0, stream>>>(timep, ev, w, fws);
    scan_kernel<<<NN, 256, 0, stream>>>(fws, ub, a, lw, lb, out);
}